// Round 10
// baseline (282.231 us; speedup 1.0000x reference)
//
#include <hip/hip_runtime.h>

// Problem constants
constexpr int B  = 16;
constexpr int LT = 512;
constexpr int D  = 1024;
constexpr int N  = 4096;
constexpr int H  = 16;
constexpr int DH = D / H;       // 64
constexpr int LMAX = N / B;     // 256
constexpr float LN_EPS = 1e-5f;

typedef short  s16x8 __attribute__((ext_vector_type(8)));
typedef float  f32x4 __attribute__((ext_vector_type(4)));

__device__ __forceinline__ unsigned short f2bf(float x) {
    unsigned int u = __float_as_uint(x);
    unsigned int r = (u + 0x7fffu + ((u >> 16) & 1u)) >> 16;   // RNE
    return (unsigned short)r;
}
__device__ __forceinline__ float bf2f(unsigned short u) {
    return __uint_as_float((unsigned int)u << 16);
}

__device__ __forceinline__ void load_lds16(const void* g, void* l) {
    __builtin_amdgcn_global_load_lds(
        (const __attribute__((address_space(1))) unsigned int*)g,
        (__attribute__((address_space(3))) unsigned int*)l, 16, 0, 0);
}

// ---------------------------------------------------------------------------
// cast3 + prep + msum-zero in one dispatch.
__global__ __launch_bounds__(256) void cast3_prep(
        const float* __restrict__ x0, unsigned short* __restrict__ y0, int n0,
        const float* __restrict__ x1, unsigned short* __restrict__ y1, int n1,
        const float* __restrict__ x2, unsigned short* __restrict__ y2, int n2,
        const int* __restrict__ sb, int* __restrict__ counts, int* __restrict__ starts,
        float* __restrict__ msum) {
    __shared__ int s_counts[B];
    int t = threadIdx.x;
    if (blockIdx.x == 6144) {   // prep
        if (t < B) s_counts[t] = 0;
        __syncthreads();
        for (int i = t; i < N; i += 256) atomicAdd(&s_counts[sb[i]], 1);
        __syncthreads();
        if (t == 0) {
            int run = 0;
            for (int b = 0; b < B; b++) { starts[b] = run; run += s_counts[b]; }
        }
        if (t < B) counts[t] = s_counts[t];
        return;
    }
    if (blockIdx.x == 6145) {   // zero msum (B*D floats = 16384)
        float4 z = {0.f, 0.f, 0.f, 0.f};
#pragma unroll
        for (int c = 0; c < 16; c++)
            ((float4*)msum)[c * 256 + t] = z;
        return;
    }
    long long i = (long long)(blockIdx.x * 256 + t) * 8;
    const float* x; unsigned short* y;
    if (i < n0)                { x = x0 + i; y = y0 + i; }
    else if (i < (long long)n0 + n1) { long long j = i - n0; x = x1 + j; y = y1 + j; }
    else if (i < (long long)n0 + n1 + n2) { long long j = i - n0 - n1; x = x2 + j; y = y2 + j; }
    else return;
    float4 a = *(const float4*)x;
    float4 b = *(const float4*)(x + 4);
    ushort4 o1, o2;
    o1.x = f2bf(a.x); o1.y = f2bf(a.y); o1.z = f2bf(a.z); o1.w = f2bf(a.w);
    o2.x = f2bf(b.x); o2.y = f2bf(b.y); o2.z = f2bf(b.z); o2.w = f2bf(b.w);
    *(ushort4*)y = o1;
    *(ushort4*)(y + 4) = o2;
}

// ---------------------------------------------------------------------------
// scatter covering ALL (b,p) slots (segment-contiguous source), zeros for pad.
__global__ void scatter_full(const float* __restrict__ st,
                             const int* __restrict__ counts,
                             const int* __restrict__ starts,
                             unsigned short* __restrict__ padded) {
    int p = blockIdx.x, b = blockIdx.y;
    int d = threadIdx.x * 4;
    size_t off = ((size_t)(b * LMAX + p)) * D + d;
    ushort4 o = {0, 0, 0, 0};
    if (p < counts[b]) {
        float4 v = *(const float4*)&st[(size_t)(starts[b] + p) * D + d];
        o.x = f2bf(v.x); o.y = f2bf(v.y); o.z = f2bf(v.z); o.w = f2bf(v.w);
    }
    *(ushort4*)&padded[off] = o;
}

// ---------------------------------------------------------------------------
// qkv GEMM core: measured-best config (71.5 us): 256x128 tile, 8 waves
// (4x2, 64x64/wave), BK=32, 48 KiB dbuf LDS, vmcnt(3/0), 2 blocks/CU.
// Verified conflict-free swizzle: LDS slot p of row r holds k-octet
// p ^ ((r>>1)&3); fragment slot = quad ^ ((fm>>1)&3). SQ_LDS_BANK_CONFLICT=0.
template<typename Epi>
__device__ __forceinline__ void gemm32(const unsigned short* __restrict__ A,
                                       const unsigned short* __restrict__ W,
                                       int K, int kbeg, int kend, int m0, int n0,
                                       unsigned short* __restrict__ As,
                                       unsigned short* __restrict__ Bs,
                                       Epi&& epi) {
    const int tid  = threadIdx.x;
    const int lane = tid & 63;
    const int wid  = tid >> 6;
    const int wr   = wid >> 1;        // 0..3
    const int wc   = wid & 1;         // 0..1
    const int fm   = lane & 15;
    const int quad = lane >> 4;
    const int NK   = (kend - kbeg) >> 5;

    f32x4 acc[4][4];
#pragma unroll
    for (int i = 0; i < 4; i++)
#pragma unroll
        for (int j = 0; j < 4; j++) acc[i][j] = (f32x4){0.f, 0.f, 0.f, 0.f};

    const int rA0 = tid >> 2,          sA0 = (tid & 3) ^ ((tid >> 3) & 3);
    const int cA1 = tid + 512;
    const int rA1 = cA1 >> 2,          sA1 = (cA1 & 3) ^ ((cA1 >> 3) & 3);
    const unsigned short* gA0 = A + (size_t)(m0 + rA0) * K + kbeg + sA0 * 8;
    const unsigned short* gA1 = A + (size_t)(m0 + rA1) * K + kbeg + sA1 * 8;
    const unsigned short* gB  = W + (size_t)(n0 + rA0) * K + kbeg + sA0 * 8;
    unsigned short* lA0 = As + (size_t)tid * 8;
    unsigned short* lA1 = As + (size_t)(tid + 512) * 8;
    unsigned short* lB  = Bs + (size_t)tid * 8;

    const int sl8 = (quad ^ ((fm >> 1) & 3)) * 8;
    int offA[4], offB[4];
#pragma unroll
    for (int i = 0; i < 4; i++) offA[i] = (wr * 64 + i * 16 + fm) * 32 + sl8;
#pragma unroll
    for (int j = 0; j < 4; j++) offB[j] = (wc * 64 + j * 16 + fm) * 32 + sl8;

    load_lds16(gA0, lA0);
    load_lds16(gA1, lA1);
    load_lds16(gB , lB );

    for (int s = 0; s < NK; s++) {
        const int ab = (s & 1) << 13;
        const int bb = (s & 1) << 12;
        asm volatile("s_barrier" ::: "memory");
        if (s + 1 < NK) {
            const int go = (s + 1) << 5;
            const int ab2 = ((s + 1) & 1) << 13;
            const int bb2 = ((s + 1) & 1) << 12;
            load_lds16(gA0 + go, lA0 + ab2);
            load_lds16(gA1 + go, lA1 + ab2);
            load_lds16(gB  + go, lB  + bb2);
            asm volatile("s_waitcnt vmcnt(3)" ::: "memory");
        } else {
            asm volatile("s_waitcnt vmcnt(0)" ::: "memory");
        }
        asm volatile("s_barrier" ::: "memory");

        s16x8 af[4], bfv[4];
#pragma unroll
        for (int i = 0; i < 4; i++) af[i] = *(const s16x8*)&As[ab + offA[i]];
#pragma unroll
        for (int j = 0; j < 4; j++) bfv[j] = *(const s16x8*)&Bs[bb + offB[j]];

        __builtin_amdgcn_s_setprio(1);
#pragma unroll
        for (int i = 0; i < 4; i++)
#pragma unroll
            for (int j = 0; j < 4; j++)
                acc[i][j] = __builtin_amdgcn_mfma_f32_16x16x32_bf16(af[i], bfv[j], acc[i][j], 0, 0, 0);
        __builtin_amdgcn_s_setprio(0);
    }

    const int fr = quad * 4;
#pragma unroll
    for (int i = 0; i < 4; i++)
#pragma unroll
        for (int j = 0; j < 4; j++) {
            int row = m0 + wr * 64 + i * 16 + fr;
            int col = n0 + wc * 64 + j * 16 + fm;
#pragma unroll
            for (int r = 0; r < 4; r++)
                epi(row + r, col, acc[i][j][r]);
        }
}

// ---------------------------------------------------------------------------
// gemm_bf2 core: 128x128 tile, 256 threads (4 waves 2x2), BK=32, 32 KiB
// dbuf, 4 blocks/CU. vmcnt(4/0).
template<typename Epi>
__device__ __forceinline__ void gemm128(const unsigned short* __restrict__ A,
                                        const unsigned short* __restrict__ W,
                                        int K, int kbeg, int kend, int m0, int n0,
                                        unsigned short* __restrict__ As,
                                        unsigned short* __restrict__ Bs,
                                        Epi&& epi) {
    const int tid  = threadIdx.x;       // 0..255
    const int lane = tid & 63;
    const int wid  = tid >> 6;          // 0..3
    const int wr   = wid >> 1;          // 0..1
    const int wc   = wid & 1;           // 0..1
    const int fm   = lane & 15;
    const int quad = lane >> 4;
    const int NK   = (kend - kbeg) >> 5;

    f32x4 acc[4][4];
#pragma unroll
    for (int i = 0; i < 4; i++)
#pragma unroll
        for (int j = 0; j < 4; j++) acc[i][j] = (f32x4){0.f, 0.f, 0.f, 0.f};

    const int r0 = tid >> 2, s0 = (tid & 3) ^ ((tid >> 3) & 3);
    const unsigned short* gA0 = A + (size_t)(m0 + r0) * K + kbeg + s0 * 8;
    const unsigned short* gA1 = gA0 + (size_t)64 * K;
    const unsigned short* gB0 = W + (size_t)(n0 + r0) * K + kbeg + s0 * 8;
    const unsigned short* gB1 = gB0 + (size_t)64 * K;
    unsigned short* lA0 = As + (size_t)tid * 8;
    unsigned short* lA1 = As + (size_t)(tid + 256) * 8;
    unsigned short* lB0 = Bs + (size_t)tid * 8;
    unsigned short* lB1 = Bs + (size_t)(tid + 256) * 8;

    const int sl8 = (quad ^ ((fm >> 1) & 3)) * 8;
    int offA[4], offB[4];
#pragma unroll
    for (int i = 0; i < 4; i++) offA[i] = (wr * 64 + i * 16 + fm) * 32 + sl8;
#pragma unroll
    for (int j = 0; j < 4; j++) offB[j] = (wc * 64 + j * 16 + fm) * 32 + sl8;

    load_lds16(gA0, lA0);
    load_lds16(gA1, lA1);
    load_lds16(gB0, lB0);
    load_lds16(gB1, lB1);

    for (int s = 0; s < NK; s++) {
        const int ab = (s & 1) << 12;
        const int bb = (s & 1) << 12;
        asm volatile("s_barrier" ::: "memory");
        if (s + 1 < NK) {
            const int go = (s + 1) << 5;
            const int nb = ((s + 1) & 1) << 12;
            load_lds16(gA0 + go, lA0 + nb);
            load_lds16(gA1 + go, lA1 + nb);
            load_lds16(gB0 + go, lB0 + nb);
            load_lds16(gB1 + go, lB1 + nb);
            asm volatile("s_waitcnt vmcnt(4)" ::: "memory");
        } else {
            asm volatile("s_waitcnt vmcnt(0)" ::: "memory");
        }
        asm volatile("s_barrier" ::: "memory");

        s16x8 af[4], bfv[4];
#pragma unroll
        for (int i = 0; i < 4; i++) af[i] = *(const s16x8*)&As[ab + offA[i]];
#pragma unroll
        for (int j = 0; j < 4; j++) bfv[j] = *(const s16x8*)&Bs[bb + offB[j]];

        __builtin_amdgcn_s_setprio(1);
#pragma unroll
        for (int i = 0; i < 4; i++)
#pragma unroll
            for (int j = 0; j < 4; j++)
                acc[i][j] = __builtin_amdgcn_mfma_f32_16x16x32_bf16(af[i], bfv[j], acc[i][j], 0, 0, 0);
        __builtin_amdgcn_s_setprio(0);
    }

    const int fr = quad * 4;
#pragma unroll
    for (int i = 0; i < 4; i++)
#pragma unroll
        for (int j = 0; j < 4; j++) {
            int row = m0 + wr * 64 + i * 16 + fr;
            int col = n0 + wc * 64 + j * 16 + fm;
#pragma unroll
            for (int r = 0; r < 4; r++)
                epi(row + r, col, acc[i][j][r]);
        }
}

// Fused QKV: 640 blocks of 512 threads (measured-best config).
// XCD swizzle (640 = 8*80).
__global__ __launch_bounds__(512, 4) void qkv_fused(const unsigned short* __restrict__ padded,
                                                    const unsigned short* __restrict__ text,
                                                    const unsigned short* __restrict__ wqkv,
                                                    const float* __restrict__ bqkv,
                                                    unsigned short* __restrict__ qpack,
                                                    unsigned short* __restrict__ kpack,
                                                    unsigned short* __restrict__ vpack) {
    __shared__ __align__(16) unsigned short As[2 * 8192];   // 32 KiB
    __shared__ __align__(16) unsigned short Bs[2 * 4096];   // 16 KiB
    int orig = blockIdx.x;
    int id = (orig & 7) * 80 + (orig >> 3);
    if (id < 128) {
        int mt = id >> 3, nt = id & 7;
        gemm32(padded, wqkv, D, 0, D, mt * 256, nt * 128, As, Bs,
            [&](int mm, int col, float v) {
                float val = v + bqkv[col];
                int b = mm >> 8, q = mm & 255;
                int h = col >> 6, d = col & 63;
                qpack[(size_t)(b * H + h) * 16384 + (d >> 3) * 2048 + q * 8 + (d & 7)] = f2bf(val);
            });
    } else if (id < 384) {
        int f = id - 128;
        int mt = f >> 3, nt = f & 7;
        gemm32(text, wqkv + (size_t)D * D, D, 0, D, mt * 256, nt * 128, As, Bs,
            [&](int mm, int col, float v) {
                float val = v + bqkv[D + col];
                int b = mm >> 9, key = mm & 511;
                int h = col >> 6, d = col & 63;
                kpack[(size_t)(b * H + h) * 32768 + (d >> 3) * 4096 + key * 8 + (d & 7)] = f2bf(val);
            });
    } else {
        int f = id - 384;
        int mt = f >> 6, nt = f & 63;
        gemm32(wqkv + 2 * (size_t)D * D, text, D, 0, D, mt * 256, nt * 128, As, Bs,
            [&](int mm, int col, float v) {
                float val = v + bqkv[2 * D + mm];
                int h = mm >> 6, d = mm & 63;
                int b = col >> 9, key = col & 511;
                vpack[(size_t)(b * H + h) * 32768 + (key >> 3) * 512 + d * 8 + (key & 7)] = f2bf(val);
            });
    }
}

// attn_out GEMM, 128^2 tiles, split-K=2 -> 512 blocks of 256 threads.
__global__ __launch_bounds__(256, 4) void gemm_bf2(const unsigned short* __restrict__ A,
                                                   const unsigned short* __restrict__ W,
                                                   unsigned short* __restrict__ C0,
                                                   unsigned short* __restrict__ C1,
                                                   int Nn, int K) {
    __shared__ __align__(16) unsigned short As[2 * 4096];   // 16 KiB
    __shared__ __align__(16) unsigned short Bs[2 * 4096];   // 16 KiB
    int orig = blockIdx.x;
    int id = (orig & 7) * 64 + (orig >> 3);   // 512 = 8*64 bijective
    int kh = id >> 8;
    int f  = id & 255;
    int mt = f >> 3, nt = f & 7;
    unsigned short* C = kh ? C1 : C0;
    gemm128(A, W, K, kh * 512, (kh + 1) * 512, mt * 128, nt * 128, As, Bs,
        [&](int mm, int col, float v) {
            C[(size_t)mm * Nn + col] = f2bf(v);
        });
}

// ---------------------------------------------------------------------------
// MFMA attention — ROUND-10 RESTRUCTURE: 4-chunk online-softmax flash loop.
// Score state shrinks sc[32]->sc[8] (-96 VGPR; cap 128 via launch_bounds)
// and KV staging becomes a 3x16KiB rotating pool (LDS 48+18 KiB = 66 KiB)
// -> 2 blocks/CU co-resident, 512-block grid fits in ONE residency round
// (was ~200 VGPR -> 1 block/CU -> 2 serialized rounds, zero overlap).
// Per chunk c: vmcnt(2) [K_c ready; V_c in flight] -> QK^T(c) -> barrier ->
// issue K_{c+1} -> online-softmax partial (running m, alpha-rescale of co,l;
// covers flight) -> vmcnt(2) [V_c ready] -> PV(c) -> barrier -> issue V_{c+1}.
// Buffer tenancy j%3: each overwrite target was barrier-retired 2 phases ago.
constexpr int PKW = 72;

__global__ __launch_bounds__(512, 4) void attn_mfma(const unsigned short* __restrict__ qpack,
                                                    const unsigned short* __restrict__ kpack,
                                                    const unsigned short* __restrict__ vpack,
                                                    unsigned short* __restrict__ ctx) {
    __shared__ __align__(16) unsigned short KV[3][8192];    // 3 x 16 KiB
    __shared__ __align__(16) unsigned short Ps[8 * 16 * PKW];

    const int tid = threadIdx.x;
    const int lane = tid & 63;
    const int wv = tid >> 6;
    const int fm = lane & 15;
    const int quad = lane >> 4;
    const int h = blockIdx.x, b = blockIdx.y, half = blockIdx.z;
    const int q0 = half * 128 + wv * 16;

    const unsigned short* qp = qpack + (size_t)(b * H + h) * 16384;
    const unsigned short* kp = kpack + (size_t)(b * H + h) * 32768;
    const unsigned short* vp = vpack + (size_t)(b * H + h) * 32768;

    const s16x8 aq0 = *(const s16x8*)&qp[quad * 2048 + (q0 + fm) * 8];
    const s16x8 aq1 = *(const s16x8*)&qp[(4 + quad) * 2048 + (q0 + fm) * 8];

    // Stage a 128-key K-chunk (8 d-octets x 128 keys) / V-chunk (16 key-octets
    // x 64 d). 1024 16B-chunks each -> 2 loads/thread.
    auto stageK = [&](int c, int bfi) {
#pragma unroll
        for (int it = 0; it < 2; it++) {
            int f = it * 512 + tid;
            load_lds16(kp + (f >> 7) * 4096 + c * 1024 + (f & 127) * 8, &KV[bfi][f * 8]);
        }
    };
    auto stageV = [&](int c, int bfi) {
#pragma unroll
        for (int it = 0; it < 2; it++) {
            int f = it * 512 + tid;
            load_lds16(vp + c * 8192 + f * 8, &KV[bfi][f * 8]);
        }
    };

    const float scale = 0.125f;
    f32x4 co[4];
#pragma unroll
    for (int n = 0; n < 4; n++) co[n] = (f32x4){0.f, 0.f, 0.f, 0.f};
    float m[4], l[4];
#pragma unroll
    for (int r = 0; r < 4; r++) { m[r] = -1e30f; l[r] = 0.f; }

    unsigned short* Pw = Ps + wv * (16 * PKW);

    stageK(0, 0);      // tenant 0 -> buf 0
    stageV(0, 1);      // tenant 1 -> buf 1

#pragma unroll
    for (int c = 0; c < 4; c++) {
        const int kb = (2 * c) % 3;          // 0,2,1,0
        const int vb = (2 * c + 1) % 3;      // 1,0,2,1

        // K_c ready (only V_c's 2 loads may remain in flight).
        asm volatile("s_waitcnt vmcnt(2)" ::: "memory");
        __builtin_amdgcn_s_barrier();

        f32x4 sc[8];
        __builtin_amdgcn_s_setprio(1);
#pragma unroll
        for (int t = 0; t < 8; t++) {
            s16x8 bk0 = *(const s16x8*)&KV[kb][quad * 1024 + (t * 16 + fm) * 8];
            s16x8 bk1 = *(const s16x8*)&KV[kb][(4 + quad) * 1024 + (t * 16 + fm) * 8];
            f32x4 a = (f32x4){0.f, 0.f, 0.f, 0.f};
            a = __builtin_amdgcn_mfma_f32_16x16x32_bf16(aq0, bk0, a, 0, 0, 0);
            a = __builtin_amdgcn_mfma_f32_16x16x32_bf16(aq1, bk1, a, 0, 0, 0);
            sc[t] = a;
        }
        __builtin_amdgcn_s_setprio(0);

        // All waves' K_c reads retired -> buf kb safe to overwrite at c+1's V.
        asm volatile("s_waitcnt lgkmcnt(0)" ::: "memory");
        __builtin_amdgcn_s_barrier();
        if (c < 3) stageK(c + 1, (2 * c + 2) % 3);

        // Online-softmax partial (covers K_{c+1}/V_c flight).
        float cm[4];
#pragma unroll
        for (int r = 0; r < 4; r++) {
            float mm = sc[0][r];
#pragma unroll
            for (int t = 1; t < 8; t++) mm = fmaxf(mm, sc[t][r]);
            cm[r] = mm;
        }
#pragma unroll
        for (int o = 1; o < 16; o <<= 1)
#pragma unroll
            for (int r = 0; r < 4; r++) cm[r] = fmaxf(cm[r], __shfl_xor(cm[r], o));
        float al[4];
#pragma unroll
        for (int r = 0; r < 4; r++) {
            float mn = fmaxf(m[r], cm[r]);
            al[r] = __expf((m[r] - mn) * scale);
            m[r] = mn;
        }
        float ls[4] = {0.f, 0.f, 0.f, 0.f};
#pragma unroll
        for (int t = 0; t < 8; t++)
#pragma unroll
            for (int r = 0; r < 4; r++) {
                float e = __expf((sc[t][r] - m[r]) * scale);
                sc[t][r] = e;
                ls[r] += e;
            }
#pragma unroll
        for (int r = 0; r < 4; r++) l[r] = l[r] * al[r] + ls[r];   // per-lane partial
#pragma unroll
        for (int n = 0; n < 4; n++)
#pragma unroll
            for (int r = 0; r < 4; r++) co[n][r] *= al[r];

        // V_c ready (K_{c+1}'s 2 loads may remain in flight).
        if (c < 3) asm volatile("s_waitcnt vmcnt(2)" ::: "memory");
        else       asm volatile("s_waitcnt vmcnt(0)" ::: "memory");
        __builtin_amdgcn_s_barrier();

#pragma unroll
        for (int cs = 0; cs < 2; cs++) {
#pragma unroll
            for (int tt = 0; tt < 4; tt++)
#pragma unroll
                for (int r = 0; r < 4; r++)
                    Pw[(quad * 4 + r) * PKW + tt * 16 + fm] = f2bf(sc[cs * 4 + tt][r]);
            __builtin_amdgcn_s_setprio(1);
#pragma unroll
            for (int s = 0; s < 2; s++) {
                s16x8 ap = *(const s16x8*)&Pw[fm * PKW + s * 32 + quad * 8];
#pragma unroll
                for (int n = 0; n < 4; n++) {
                    s16x8 bv = *(const s16x8*)&KV[vb][(cs * 8 + s * 4 + quad) * 512 + (n * 16 + fm) * 8];
                    co[n] = __builtin_amdgcn_mfma_f32_16x16x32_bf16(ap, bv, co[n], 0, 0, 0);
                }
            }
            __builtin_amdgcn_s_setprio(0);
        }

        // All waves' V_c reads retired -> buf vb safe to overwrite at c+1's K.
        asm volatile("s_waitcnt lgkmcnt(0)" ::: "memory");
        __builtin_amdgcn_s_barrier();
        if (c < 3) stageV(c + 1, (2 * c + 3) % 3);
    }

    // Final denominator: reduce per-lane partial l across the 16 col-lanes.
    float inv[4];
#pragma unroll
    for (int o = 1; o < 16; o <<= 1)
#pragma unroll
        for (int r = 0; r < 4; r++) l[r] += __shfl_xor(l[r], o);
#pragma unroll
    for (int r = 0; r < 4; r++) inv[r] = 1.f / l[r];

    const size_t obase = (size_t)(b * LMAX + q0) * D + h * DH;
#pragma unroll
    for (int n = 0; n < 4; n++)
#pragma unroll
        for (int r = 0; r < 4; r++)
            ctx[obase + (size_t)(quad * 4 + r) * D + n * 16 + fm] = f2bf(co[n][r] * inv[r]);
}

// ---------------------------------------------------------------------------
// Barrier-free fused (partial-sum + bias) + LayerNorm + segment-mean.
// Grid (B,8) — the proven config.
__global__ __launch_bounds__(256) void lnmean_kernel(const unsigned short* __restrict__ f1a,
                                                     const unsigned short* __restrict__ f1b,
                                                     const float* __restrict__ bo,
                                                     const float* __restrict__ g,
                                                     const float* __restrict__ bb,
                                                     const int* __restrict__ counts,
                                                     float* __restrict__ msum) {
    int b = blockIdx.x;
    int t = threadIdx.x;
    int wv = t >> 6, lane = t & 63;
    int cnt = counts[b];
    int s0 = blockIdx.y * 32 + wv * 8;
    int s1 = min(cnt, s0 + 8);

    float4 gg[4], bv[4], bo4[4];
#pragma unroll
    for (int c = 0; c < 4; c++) {
        gg[c]  = *(const float4*)&g[c * 256 + lane * 4];
        bv[c]  = *(const float4*)&bb[c * 256 + lane * 4];
        bo4[c] = *(const float4*)&bo[c * 256 + lane * 4];
    }
    float4 acc[4];
#pragma unroll
    for (int c = 0; c < 4; c++) acc[c] = (float4){0.f, 0.f, 0.f, 0.f};

    for (int s = s0; s < s1; s++) {
        size_t rbase = ((size_t)(b * LMAX + s)) * D;
        float4 v[4];
        float sm = 0.f, ss = 0.f;
#pragma unroll
        for (int c = 0; c < 4; c++) {
            ushort4 ua = *(const ushort4*)&f1a[rbase + c * 256 + lane * 4];
            ushort4 ub = *(const ushort4*)&f1b[rbase + c * 256 + lane * 4];
            v[c].x = bf2f(ua.x) + bf2f(ub.x) + bo4[c].x;
            v[c].y = bf2f(ua.y) + bf2f(ub.y) + bo4[c].y;
            v[c].z = bf2f(ua.z) + bf2f(ub.z) + bo4[c].z;
            v[c].w = bf2f(ua.w) + bf2f(ub.w) + bo4[c].w;
            sm += v[c].x + v[c].y + v[c].z + v[c].w;
            ss += v[c].x * v[c].x + v[c].y * v[c].y + v[c].z * v[c].z + v[c].w * v[c].w;
        }
#pragma unroll
        for (int o = 32; o; o >>= 1) { sm += __shfl_xor(sm, o); ss += __shfl_xor(ss, o); }
        float mu = sm * (1.f / D);
        float var = ss * (1.f / D) - mu * mu;
        float r = rsqrtf(var + LN_EPS);
#pragma unroll
        for (int c = 0; c < 4; c++) {
            acc[c].x += (v[c].x - mu) * r * gg[c].x + bv[c].x;
            acc[c].y += (v[c].y - mu) * r * gg[c].y + bv[c].y;
            acc[c].z += (v[c].z - mu) * r * gg[c].z + bv[c].z;
            acc[c].w += (v[c].w - mu) * r * gg[c].w + bv[c].w;
        }
    }
    float inv = 1.f / (float)max(cnt, 1);
#pragma unroll
    for (int c = 0; c < 4; c++) {
        int base = b * D + c * 256 + lane * 4;
        atomicAdd(&msum[base + 0], acc[c].x * inv);
        atomicAdd(&msum[base + 1], acc[c].y * inv);
        atomicAdd(&msum[base + 2], acc[c].z * inv);
        atomicAdd(&msum[base + 3], acc[c].w * inv);
    }
}

// Mini projection: out[b][n] = msum[b] . proj_w[n] + bias[n]  (fp32).
__global__ __launch_bounds__(256) void tproj_kernel(const float* __restrict__ msum,
                                                    const float* __restrict__ W,
                                                    const float* __restrict__ bias,
                                                    float* __restrict__ out) {
    int lane = threadIdx.x & 63;
    int n = blockIdx.x * 4 + (threadIdx.x >> 6);
    float4 wr[4];
#pragma unroll
    for (int i = 0; i < 4; i++)
        wr[i] = *(const float4*)&W[(size_t)n * D + i * 256 + lane * 4];
    float bn = bias[n];
    for (int b = 0; b < B; b++) {
        float s = 0.f;
#pragma unroll
        for (int i = 0; i < 4; i++) {
            float4 m4 = *(const float4*)&msum[(size_t)b * D + i * 256 + lane * 4];
            s += m4.x * wr[i].x + m4.y * wr[i].y + m4.z * wr[i].z + m4.w * wr[i].w;
        }
#pragma unroll
        for (int o = 32; o; o >>= 1) s += __shfl_xor(s, o);
        if (lane == 0) out[(size_t)b * D + n] = s + bn;
    }
}

// ---------------------------------------------------------------------------
extern "C" void kernel_launch(void* const* d_in, const int* in_sizes, int n_in,
                              void* d_out, int out_size, void* d_ws, size_t ws_size,
                              hipStream_t stream) {
    const float* struct_token = (const float*)d_in[0];
    const float* text_token   = (const float*)d_in[1];
    const float* in_proj_w    = (const float*)d_in[2];
    const float* in_proj_b    = (const float*)d_in[3];
    const float* attn_out_w   = (const float*)d_in[4];
    const float* attn_out_b   = (const float*)d_in[5];
    const float* ln_g         = (const float*)d_in[6];
    const float* ln_b         = (const float*)d_in[7];
    const float* proj_w       = (const float*)d_in[8];
    const float* proj_b       = (const float*)d_in[9];
    const int*   sb           = (const int*)d_in[10];
    float* out = (float*)d_out;

    const size_t MQ  = (size_t)B * LMAX;     // 4096
    const size_t MKV = (size_t)B * LT;       // 8192

    char* p = (char*)d_ws;
    unsigned short* padded_b = (unsigned short*)p;  p += MQ * D * 2;
    unsigned short* text_b   = (unsigned short*)p;  p += MKV * D * 2;
    unsigned short* wqkv_b   = (unsigned short*)p;  p += (size_t)3 * D * D * 2;
    unsigned short* wattn_b  = (unsigned short*)p;  p += (size_t)D * D * 2;
    unsigned short* qpack    = (unsigned short*)p;  p += MQ * D * 2;
    unsigned short* kpack    = (unsigned short*)p;  p += MKV * D * 2;
    unsigned short* vpack    = (unsigned short*)p;  p += MKV * D * 2;
    unsigned short* ctx_b    = (unsigned short*)p;  p += MQ * D * 2;
    unsigned short* f1a      = (unsigned short*)p;  p += MQ * D * 2;
    unsigned short* f1b      = (unsigned short*)p;  p += MQ * D * 2;
    float* msum = (float*)p;  p += (size_t)B * D * 4;
    int* counts = (int*)p;  p += B * 4;
    int* starts = (int*)p;  p += B * 4;

    cast3_prep<<<6146, 256, 0, stream>>>(
        text_token, text_b, (int)(MKV * D),
        in_proj_w,  wqkv_b, 3 * D * D,
        attn_out_w, wattn_b, D * D,
        sb, counts, starts, msum);

    scatter_full<<<dim3(LMAX, B), 256, 0, stream>>>(struct_token, counts, starts, padded_b);

    qkv_fused<<<640, 512, 0, stream>>>(padded_b, text_b, wqkv_b, in_proj_b,
                                       qpack, kpack, vpack);

    attn_mfma<<<dim3(H, B, 2), 512, 0, stream>>>(qpack, kpack, vpack, ctx_b);

    // attn_out projection, 128^2 tiles, split-K=2 -> two bf16 partial buffers
    gemm_bf2<<<512, 256, 0, stream>>>(ctx_b, wattn_b, f1a, f1b, D, D);

    lnmean_kernel<<<dim3(B, 8), 256, 0, stream>>>(f1a, f1b, attn_out_b, ln_g, ln_b, counts, msum);

    tproj_kernel<<<256, 256, 0, stream>>>(msum, proj_w, proj_b, out);
}

// Round 11
// 247.290 us; speedup vs baseline: 1.1413x; 1.1413x over previous
//
#include <hip/hip_runtime.h>

// Problem constants
constexpr int B  = 16;
constexpr int LT = 512;
constexpr int D  = 1024;
constexpr int N  = 4096;
constexpr int H  = 16;
constexpr int DH = D / H;       // 64
constexpr int LMAX = N / B;     // 256
constexpr float LN_EPS = 1e-5f;

typedef short  s16x8 __attribute__((ext_vector_type(8)));
typedef float  f32x4 __attribute__((ext_vector_type(4)));

__device__ __forceinline__ unsigned short f2bf(float x) {
    unsigned int u = __float_as_uint(x);
    unsigned int r = (u + 0x7fffu + ((u >> 16) & 1u)) >> 16;   // RNE
    return (unsigned short)r;
}
__device__ __forceinline__ float bf2f(unsigned short u) {
    return __uint_as_float((unsigned int)u << 16);
}

__device__ __forceinline__ void load_lds16(const void* g, void* l) {
    __builtin_amdgcn_global_load_lds(
        (const __attribute__((address_space(1))) unsigned int*)g,
        (__attribute__((address_space(3))) unsigned int*)l, 16, 0, 0);
}

// ---------------------------------------------------------------------------
// cast3 + prep + msum-zero in one dispatch.
__global__ __launch_bounds__(256) void cast3_prep(
        const float* __restrict__ x0, unsigned short* __restrict__ y0, int n0,
        const float* __restrict__ x1, unsigned short* __restrict__ y1, int n1,
        const float* __restrict__ x2, unsigned short* __restrict__ y2, int n2,
        const int* __restrict__ sb, int* __restrict__ counts, int* __restrict__ starts,
        float* __restrict__ msum) {
    __shared__ int s_counts[B];
    int t = threadIdx.x;
    if (blockIdx.x == 6144) {   // prep
        if (t < B) s_counts[t] = 0;
        __syncthreads();
        for (int i = t; i < N; i += 256) atomicAdd(&s_counts[sb[i]], 1);
        __syncthreads();
        if (t == 0) {
            int run = 0;
            for (int b = 0; b < B; b++) { starts[b] = run; run += s_counts[b]; }
        }
        if (t < B) counts[t] = s_counts[t];
        return;
    }
    if (blockIdx.x == 6145) {   // zero msum (B*D floats = 16384)
        float4 z = {0.f, 0.f, 0.f, 0.f};
#pragma unroll
        for (int c = 0; c < 16; c++)
            ((float4*)msum)[c * 256 + t] = z;
        return;
    }
    long long i = (long long)(blockIdx.x * 256 + t) * 8;
    const float* x; unsigned short* y;
    if (i < n0)                { x = x0 + i; y = y0 + i; }
    else if (i < (long long)n0 + n1) { long long j = i - n0; x = x1 + j; y = y1 + j; }
    else if (i < (long long)n0 + n1 + n2) { long long j = i - n0 - n1; x = x2 + j; y = y2 + j; }
    else return;
    float4 a = *(const float4*)x;
    float4 b = *(const float4*)(x + 4);
    ushort4 o1, o2;
    o1.x = f2bf(a.x); o1.y = f2bf(a.y); o1.z = f2bf(a.z); o1.w = f2bf(a.w);
    o2.x = f2bf(b.x); o2.y = f2bf(b.y); o2.z = f2bf(b.z); o2.w = f2bf(b.w);
    *(ushort4*)y = o1;
    *(ushort4*)(y + 4) = o2;
}

// ---------------------------------------------------------------------------
// scatter covering ALL (b,p) slots (segment-contiguous source), zeros for pad.
__global__ void scatter_full(const float* __restrict__ st,
                             const int* __restrict__ counts,
                             const int* __restrict__ starts,
                             unsigned short* __restrict__ padded) {
    int p = blockIdx.x, b = blockIdx.y;
    int d = threadIdx.x * 4;
    size_t off = ((size_t)(b * LMAX + p)) * D + d;
    ushort4 o = {0, 0, 0, 0};
    if (p < counts[b]) {
        float4 v = *(const float4*)&st[(size_t)(starts[b] + p) * D + d];
        o.x = f2bf(v.x); o.y = f2bf(v.y); o.z = f2bf(v.z); o.w = f2bf(v.w);
    }
    *(ushort4*)&padded[off] = o;
}

// ---------------------------------------------------------------------------
// 128x128-tile GEMM, 256 threads (4 waves 2x2, 64x64/wave), BK=32, 32 KiB
// dbuf LDS, <=128 unified regs -> 4 blocks/CU co-resident.
// qkv grid = 1280 uniform blocks = exactly 5.0/CU (best-measured-total
// config, r8: 248.3 us). Verified conflict-free swizzle: LDS slot p of
// row r holds k-octet p ^ ((r>>1)&3); fragment slot = quad ^ ((fm>>1)&3).
// vmcnt(4/0). SQ_LDS_BANK_CONFLICT = 0.
template<typename Epi>
__device__ __forceinline__ void gemm128(const unsigned short* __restrict__ A,
                                        const unsigned short* __restrict__ W,
                                        int K, int kbeg, int kend, int m0, int n0,
                                        unsigned short* __restrict__ As,
                                        unsigned short* __restrict__ Bs,
                                        Epi&& epi) {
    const int tid  = threadIdx.x;       // 0..255
    const int lane = tid & 63;
    const int wid  = tid >> 6;          // 0..3
    const int wr   = wid >> 1;          // 0..1
    const int wc   = wid & 1;           // 0..1
    const int fm   = lane & 15;
    const int quad = lane >> 4;
    const int NK   = (kend - kbeg) >> 5;

    f32x4 acc[4][4];
#pragma unroll
    for (int i = 0; i < 4; i++)
#pragma unroll
        for (int j = 0; j < 4; j++) acc[i][j] = (f32x4){0.f, 0.f, 0.f, 0.f};

    // chunks: 512 per tile; this thread owns ci = tid and tid+256.
    // row = ci>>2; slot = (ci&3)^((ci>>3)&3); ci+256 -> row+64, same slot.
    const int r0 = tid >> 2, s0 = (tid & 3) ^ ((tid >> 3) & 3);
    const unsigned short* gA0 = A + (size_t)(m0 + r0) * K + kbeg + s0 * 8;
    const unsigned short* gA1 = gA0 + (size_t)64 * K;
    const unsigned short* gB0 = W + (size_t)(n0 + r0) * K + kbeg + s0 * 8;
    const unsigned short* gB1 = gB0 + (size_t)64 * K;
    unsigned short* lA0 = As + (size_t)tid * 8;
    unsigned short* lA1 = As + (size_t)(tid + 256) * 8;
    unsigned short* lB0 = Bs + (size_t)tid * 8;
    unsigned short* lB1 = Bs + (size_t)(tid + 256) * 8;

    const int sl8 = (quad ^ ((fm >> 1) & 3)) * 8;
    int offA[4], offB[4];
#pragma unroll
    for (int i = 0; i < 4; i++) offA[i] = (wr * 64 + i * 16 + fm) * 32 + sl8;
#pragma unroll
    for (int j = 0; j < 4; j++) offB[j] = (wc * 64 + j * 16 + fm) * 32 + sl8;

    load_lds16(gA0, lA0);
    load_lds16(gA1, lA1);
    load_lds16(gB0, lB0);
    load_lds16(gB1, lB1);

    for (int s = 0; s < NK; s++) {
        const int ab = (s & 1) << 12;     // 4096-element buffers
        const int bb = (s & 1) << 12;
        asm volatile("s_barrier" ::: "memory");
        if (s + 1 < NK) {
            const int go = (s + 1) << 5;
            const int nb = ((s + 1) & 1) << 12;
            load_lds16(gA0 + go, lA0 + nb);
            load_lds16(gA1 + go, lA1 + nb);
            load_lds16(gB0 + go, lB0 + nb);
            load_lds16(gB1 + go, lB1 + nb);
            asm volatile("s_waitcnt vmcnt(4)" ::: "memory");  // tile s retired
        } else {
            asm volatile("s_waitcnt vmcnt(0)" ::: "memory");
        }
        asm volatile("s_barrier" ::: "memory");

        s16x8 af[4], bfv[4];
#pragma unroll
        for (int i = 0; i < 4; i++) af[i] = *(const s16x8*)&As[ab + offA[i]];
#pragma unroll
        for (int j = 0; j < 4; j++) bfv[j] = *(const s16x8*)&Bs[bb + offB[j]];

        __builtin_amdgcn_s_setprio(1);
#pragma unroll
        for (int i = 0; i < 4; i++)
#pragma unroll
            for (int j = 0; j < 4; j++)
                acc[i][j] = __builtin_amdgcn_mfma_f32_16x16x32_bf16(af[i], bfv[j], acc[i][j], 0, 0, 0);
        __builtin_amdgcn_s_setprio(0);
    }

    const int fr = quad * 4;
#pragma unroll
    for (int i = 0; i < 4; i++)
#pragma unroll
        for (int j = 0; j < 4; j++) {
            int row = m0 + wr * 64 + i * 16 + fr;
            int col = n0 + wc * 64 + j * 16 + fm;
#pragma unroll
            for (int r = 0; r < 4; r++)
                epi(row + r, col, acc[i][j][r]);
        }
}

// Fused QKV: 1280 blocks of 256 threads (128^2 tiles), 4 blocks/CU,
// exactly 5 blocks per CU total. XCD swizzle (1280 = 8*160).
//   Q: ids    0..255  (32 mt x 8 nt),  M=4096 N=1024
//   K: ids  256..767  (64 x 8),        M=8192 N=1024
//   V: ids 768..1279  (8 x 64),        M=1024(d) N=8192(key)
__global__ __launch_bounds__(256, 4) void qkv_fused(const unsigned short* __restrict__ padded,
                                                    const unsigned short* __restrict__ text,
                                                    const unsigned short* __restrict__ wqkv,
                                                    const float* __restrict__ bqkv,
                                                    unsigned short* __restrict__ qpack,
                                                    unsigned short* __restrict__ kpack,
                                                    unsigned short* __restrict__ vpack) {
    __shared__ __align__(16) unsigned short As[2 * 4096];   // 16 KiB
    __shared__ __align__(16) unsigned short Bs[2 * 4096];   // 16 KiB
    int orig = blockIdx.x;
    int id = (orig & 7) * 160 + (orig >> 3);
    if (id < 256) {
        int mt = id >> 3, nt = id & 7;
        gemm128(padded, wqkv, D, 0, D, mt * 128, nt * 128, As, Bs,
            [&](int mm, int col, float v) {
                float val = v + bqkv[col];
                int b = mm >> 8, q = mm & 255;
                int h = col >> 6, d = col & 63;
                qpack[(size_t)(b * H + h) * 16384 + (d >> 3) * 2048 + q * 8 + (d & 7)] = f2bf(val);
            });
    } else if (id < 768) {
        int f = id - 256;
        int mt = f >> 3, nt = f & 7;
        gemm128(text, wqkv + (size_t)D * D, D, 0, D, mt * 128, nt * 128, As, Bs,
            [&](int mm, int col, float v) {
                float val = v + bqkv[D + col];
                int b = mm >> 9, key = mm & 511;
                int h = col >> 6, d = col & 63;
                kpack[(size_t)(b * H + h) * 32768 + (d >> 3) * 4096 + key * 8 + (d & 7)] = f2bf(val);
            });
    } else {
        int f = id - 768;
        int mt = f >> 6, nt = f & 63;
        gemm128(wqkv + 2 * (size_t)D * D, text, D, 0, D, mt * 128, nt * 128, As, Bs,
            [&](int mm, int col, float v) {
                float val = v + bqkv[2 * D + mm];
                int h = mm >> 6, d = mm & 63;
                int b = col >> 9, key = col & 511;
                vpack[(size_t)(b * H + h) * 32768 + (key >> 3) * 512 + d * 8 + (key & 7)] = f2bf(val);
            });
    }
}

// attn_out GEMM, 128^2 tiles, split-K=2 -> 512 blocks of 256 threads,
// 2 blocks/CU exact. bf16 partial outputs (no bias; added in lnmean).
__global__ __launch_bounds__(256, 4) void gemm_bf2(const unsigned short* __restrict__ A,
                                                   const unsigned short* __restrict__ W,
                                                   unsigned short* __restrict__ C0,
                                                   unsigned short* __restrict__ C1,
                                                   int Nn, int K) {
    __shared__ __align__(16) unsigned short As[2 * 4096];   // 16 KiB
    __shared__ __align__(16) unsigned short Bs[2 * 4096];   // 16 KiB
    int orig = blockIdx.x;
    int id = (orig & 7) * 64 + (orig >> 3);   // 512 = 8*64 bijective
    int kh = id >> 8;
    int f  = id & 255;
    int mt = f >> 3, nt = f & 7;
    unsigned short* C = kh ? C1 : C0;
    gemm128(A, W, K, kh * 512, (kh + 1) * 512, mt * 128, nt * 128, As, Bs,
        [&](int mm, int col, float v) {
            C[(size_t)mm * Nn + col] = f2bf(v);
        });
}

// ---------------------------------------------------------------------------
// MFMA attention (issue-early/wait-late structure — the measured-best attn;
// the r10 flash restructure with 4x the sync points regressed 28 us and
// was reverted).
constexpr int PKW = 72;

__global__ __launch_bounds__(512) void attn_mfma(const unsigned short* __restrict__ qpack,
                                                 const unsigned short* __restrict__ kpack,
                                                 const unsigned short* __restrict__ vpack,
                                                 unsigned short* __restrict__ ctx) {
    __shared__ __align__(16) unsigned short KV[2][16384];   // 64 KiB
    __shared__ __align__(16) unsigned short Ps[8 * 16 * PKW];

    const int tid = threadIdx.x;
    const int lane = tid & 63;
    const int wv = tid >> 6;
    const int fm = lane & 15;
    const int quad = lane >> 4;
    const int h = blockIdx.x, b = blockIdx.y, half = blockIdx.z;
    const int q0 = half * 128 + wv * 16;

    const unsigned short* qp = qpack + (size_t)(b * H + h) * 16384;
    const unsigned short* kp = kpack + (size_t)(b * H + h) * 32768;
    const unsigned short* vp = vpack + (size_t)(b * H + h) * 32768;

    const s16x8 aq0 = *(const s16x8*)&qp[quad * 2048 + (q0 + fm) * 8];
    const s16x8 aq1 = *(const s16x8*)&qp[(4 + quad) * 2048 + (q0 + fm) * 8];

    // Stage BOTH K halves immediately (8 gload_lds/thread, all in flight).
#pragma unroll
    for (int kc = 0; kc < 2; kc++)
#pragma unroll
        for (int it = 0; it < 4; it++) {
            int f = it * 512 + tid;
            load_lds16(kp + (f >> 8) * 4096 + kc * 2048 + (f & 255) * 8, &KV[kc][f * 8]);
        }

    f32x4 sc[32];

    asm volatile("s_waitcnt vmcnt(4)" ::: "memory");
    __builtin_amdgcn_s_barrier();
    __builtin_amdgcn_s_setprio(1);
#pragma unroll
    for (int t = 0; t < 16; t++) {
        s16x8 bk0 = *(const s16x8*)&KV[0][quad * 2048 + (t * 16 + fm) * 8];
        s16x8 bk1 = *(const s16x8*)&KV[0][(4 + quad) * 2048 + (t * 16 + fm) * 8];
        f32x4 a = (f32x4){0.f, 0.f, 0.f, 0.f};
        a = __builtin_amdgcn_mfma_f32_16x16x32_bf16(aq0, bk0, a, 0, 0, 0);
        a = __builtin_amdgcn_mfma_f32_16x16x32_bf16(aq1, bk1, a, 0, 0, 0);
        sc[t] = a;
    }
    __builtin_amdgcn_s_setprio(0);

    asm volatile("s_waitcnt vmcnt(0)" ::: "memory");
    __builtin_amdgcn_s_barrier();
    __builtin_amdgcn_s_setprio(1);
#pragma unroll
    for (int t = 0; t < 16; t++) {
        s16x8 bk0 = *(const s16x8*)&KV[1][quad * 2048 + (t * 16 + fm) * 8];
        s16x8 bk1 = *(const s16x8*)&KV[1][(4 + quad) * 2048 + (t * 16 + fm) * 8];
        f32x4 a = (f32x4){0.f, 0.f, 0.f, 0.f};
        a = __builtin_amdgcn_mfma_f32_16x16x32_bf16(aq0, bk0, a, 0, 0, 0);
        a = __builtin_amdgcn_mfma_f32_16x16x32_bf16(aq1, bk1, a, 0, 0, 0);
        sc[16 + t] = a;
    }
    __builtin_amdgcn_s_setprio(0);

    asm volatile("s_waitcnt lgkmcnt(0)" ::: "memory");
    __builtin_amdgcn_s_barrier();

    // Issue ALL V loads now; softmax below covers their HBM latency.
#pragma unroll
    for (int vc = 0; vc < 2; vc++)
#pragma unroll
        for (int it = 0; it < 4; it++) {
            int f = it * 512 + tid;
            load_lds16(vp + vc * 16384 + f * 8, &KV[vc][f * 8]);
        }

    const float scale = 0.125f;
    float mx[4], l[4], inv[4];
#pragma unroll
    for (int r = 0; r < 4; r++) {
        float m = sc[0][r];
#pragma unroll
        for (int t = 1; t < 32; t++) m = fmaxf(m, sc[t][r]);
        mx[r] = m;
    }
#pragma unroll
    for (int o = 1; o < 16; o <<= 1)
#pragma unroll
        for (int r = 0; r < 4; r++) mx[r] = fmaxf(mx[r], __shfl_xor(mx[r], o));
#pragma unroll
    for (int r = 0; r < 4; r++) l[r] = 0.f;
#pragma unroll
    for (int t = 0; t < 32; t++)
#pragma unroll
        for (int r = 0; r < 4; r++) {
            float e = __expf((sc[t][r] - mx[r]) * scale);
            sc[t][r] = e;
            l[r] += e;
        }
#pragma unroll
    for (int o = 1; o < 16; o <<= 1)
#pragma unroll
        for (int r = 0; r < 4; r++) l[r] += __shfl_xor(l[r], o);
#pragma unroll
    for (int r = 0; r < 4; r++) inv[r] = 1.f / l[r];

    f32x4 co[4];
#pragma unroll
    for (int n = 0; n < 4; n++) co[n] = (f32x4){0.f, 0.f, 0.f, 0.f};
    unsigned short* Pw = Ps + wv * (16 * PKW);

    asm volatile("s_waitcnt vmcnt(4)" ::: "memory");
    __builtin_amdgcn_s_barrier();

    for (int vc = 0; vc < 2; vc++) {
        if (vc == 1) {
            asm volatile("s_waitcnt vmcnt(0)" ::: "memory");
            __builtin_amdgcn_s_barrier();
        }
        for (int cs = 0; cs < 4; cs++) {
            int c = vc * 4 + cs;
#pragma unroll
            for (int tt = 0; tt < 4; tt++)
#pragma unroll
                for (int r = 0; r < 4; r++)
                    Pw[(quad * 4 + r) * PKW + tt * 16 + fm] = f2bf(sc[c * 4 + tt][r]);
            __builtin_amdgcn_s_setprio(1);
#pragma unroll
            for (int s = 0; s < 2; s++) {
                s16x8 ap = *(const s16x8*)&Pw[fm * PKW + s * 32 + quad * 8];
#pragma unroll
                for (int n = 0; n < 4; n++) {
                    s16x8 bv = *(const s16x8*)&KV[vc][(cs * 8 + s * 4 + quad) * 512 + (n * 16 + fm) * 8];
                    co[n] = __builtin_amdgcn_mfma_f32_16x16x32_bf16(ap, bv, co[n], 0, 0, 0);
                }
            }
            __builtin_amdgcn_s_setprio(0);
        }
    }

    const size_t obase = (size_t)(b * LMAX + q0) * D + h * DH;
#pragma unroll
    for (int n = 0; n < 4; n++)
#pragma unroll
        for (int r = 0; r < 4; r++)
            ctx[obase + (size_t)(quad * 4 + r) * D + n * 16 + fm] = f2bf(co[n][r] * inv[r]);
}

// ---------------------------------------------------------------------------
// Barrier-free fused (partial-sum + bias) + LayerNorm + segment-mean.
// Grid (B,8) — the proven config.
__global__ __launch_bounds__(256) void lnmean_kernel(const unsigned short* __restrict__ f1a,
                                                     const unsigned short* __restrict__ f1b,
                                                     const float* __restrict__ bo,
                                                     const float* __restrict__ g,
                                                     const float* __restrict__ bb,
                                                     const int* __restrict__ counts,
                                                     float* __restrict__ msum) {
    int b = blockIdx.x;
    int t = threadIdx.x;
    int wv = t >> 6, lane = t & 63;
    int cnt = counts[b];
    int s0 = blockIdx.y * 32 + wv * 8;
    int s1 = min(cnt, s0 + 8);

    float4 gg[4], bv[4], bo4[4];
#pragma unroll
    for (int c = 0; c < 4; c++) {
        gg[c]  = *(const float4*)&g[c * 256 + lane * 4];
        bv[c]  = *(const float4*)&bb[c * 256 + lane * 4];
        bo4[c] = *(const float4*)&bo[c * 256 + lane * 4];
    }
    float4 acc[4];
#pragma unroll
    for (int c = 0; c < 4; c++) acc[c] = (float4){0.f, 0.f, 0.f, 0.f};

    for (int s = s0; s < s1; s++) {
        size_t rbase = ((size_t)(b * LMAX + s)) * D;
        float4 v[4];
        float sm = 0.f, ss = 0.f;
#pragma unroll
        for (int c = 0; c < 4; c++) {
            ushort4 ua = *(const ushort4*)&f1a[rbase + c * 256 + lane * 4];
            ushort4 ub = *(const ushort4*)&f1b[rbase + c * 256 + lane * 4];
            v[c].x = bf2f(ua.x) + bf2f(ub.x) + bo4[c].x;
            v[c].y = bf2f(ua.y) + bf2f(ub.y) + bo4[c].y;
            v[c].z = bf2f(ua.z) + bf2f(ub.z) + bo4[c].z;
            v[c].w = bf2f(ua.w) + bf2f(ub.w) + bo4[c].w;
            sm += v[c].x + v[c].y + v[c].z + v[c].w;
            ss += v[c].x * v[c].x + v[c].y * v[c].y + v[c].z * v[c].z + v[c].w * v[c].w;
        }
#pragma unroll
        for (int o = 32; o; o >>= 1) { sm += __shfl_xor(sm, o); ss += __shfl_xor(ss, o); }
        float mu = sm * (1.f / D);
        float var = ss * (1.f / D) - mu * mu;
        float r = rsqrtf(var + LN_EPS);
#pragma unroll
        for (int c = 0; c < 4; c++) {
            acc[c].x += (v[c].x - mu) * r * gg[c].x + bv[c].x;
            acc[c].y += (v[c].y - mu) * r * gg[c].y + bv[c].y;
            acc[c].z += (v[c].z - mu) * r * gg[c].z + bv[c].z;
            acc[c].w += (v[c].w - mu) * r * gg[c].w + bv[c].w;
        }
    }
    float inv = 1.f / (float)max(cnt, 1);
#pragma unroll
    for (int c = 0; c < 4; c++) {
        int base = b * D + c * 256 + lane * 4;
        atomicAdd(&msum[base + 0], acc[c].x * inv);
        atomicAdd(&msum[base + 1], acc[c].y * inv);
        atomicAdd(&msum[base + 2], acc[c].z * inv);
        atomicAdd(&msum[base + 3], acc[c].w * inv);
    }
}

// Mini projection: out[b][n] = msum[b] . proj_w[n] + bias[n]  (fp32).
__global__ __launch_bounds__(256) void tproj_kernel(const float* __restrict__ msum,
                                                    const float* __restrict__ W,
                                                    const float* __restrict__ bias,
                                                    float* __restrict__ out) {
    int lane = threadIdx.x & 63;
    int n = blockIdx.x * 4 + (threadIdx.x >> 6);
    float4 wr[4];
#pragma unroll
    for (int i = 0; i < 4; i++)
        wr[i] = *(const float4*)&W[(size_t)n * D + i * 256 + lane * 4];
    float bn = bias[n];
    for (int b = 0; b < B; b++) {
        float s = 0.f;
#pragma unroll
        for (int i = 0; i < 4; i++) {
            float4 m4 = *(const float4*)&msum[(size_t)b * D + i * 256 + lane * 4];
            s += m4.x * wr[i].x + m4.y * wr[i].y + m4.z * wr[i].z + m4.w * wr[i].w;
        }
#pragma unroll
        for (int o = 32; o; o >>= 1) s += __shfl_xor(s, o);
        if (lane == 0) out[(size_t)b * D + n] = s + bn;
    }
}

// ---------------------------------------------------------------------------
extern "C" void kernel_launch(void* const* d_in, const int* in_sizes, int n_in,
                              void* d_out, int out_size, void* d_ws, size_t ws_size,
                              hipStream_t stream) {
    const float* struct_token = (const float*)d_in[0];
    const float* text_token   = (const float*)d_in[1];
    const float* in_proj_w    = (const float*)d_in[2];
    const float* in_proj_b    = (const float*)d_in[3];
    const float* attn_out_w   = (const float*)d_in[4];
    const float* attn_out_b   = (const float*)d_in[5];
    const float* ln_g         = (const float*)d_in[6];
    const float* ln_b         = (const float*)d_in[7];
    const float* proj_w       = (const float*)d_in[8];
    const float* proj_b       = (const float*)d_in[9];
    const int*   sb           = (const int*)d_in[10];
    float* out = (float*)d_out;

    const size_t MQ  = (size_t)B * LMAX;     // 4096
    const size_t MKV = (size_t)B * LT;       // 8192

    char* p = (char*)d_ws;
    unsigned short* padded_b = (unsigned short*)p;  p += MQ * D * 2;
    unsigned short* text_b   = (unsigned short*)p;  p += MKV * D * 2;
    unsigned short* wqkv_b   = (unsigned short*)p;  p += (size_t)3 * D * D * 2;
    unsigned short* wattn_b  = (unsigned short*)p;  p += (size_t)D * D * 2;
    unsigned short* qpack    = (unsigned short*)p;  p += MQ * D * 2;
    unsigned short* kpack    = (unsigned short*)p;  p += MKV * D * 2;
    unsigned short* vpack    = (unsigned short*)p;  p += MKV * D * 2;
    unsigned short* ctx_b    = (unsigned short*)p;  p += MQ * D * 2;
    unsigned short* f1a      = (unsigned short*)p;  p += MQ * D * 2;
    unsigned short* f1b      = (unsigned short*)p;  p += MQ * D * 2;
    float* msum = (float*)p;  p += (size_t)B * D * 4;
    int* counts = (int*)p;  p += B * 4;
    int* starts = (int*)p;  p += B * 4;

    cast3_prep<<<6146, 256, 0, stream>>>(
        text_token, text_b, (int)(MKV * D),
        in_proj_w,  wqkv_b, 3 * D * D,
        attn_out_w, wattn_b, D * D,
        sb, counts, starts, msum);

    scatter_full<<<dim3(LMAX, B), 256, 0, stream>>>(struct_token, counts, starts, padded_b);

    qkv_fused<<<1280, 256, 0, stream>>>(padded_b, text_b, wqkv_b, in_proj_b,
                                        qpack, kpack, vpack);

    attn_mfma<<<dim3(H, B, 2), 512, 0, stream>>>(qpack, kpack, vpack, ctx_b);

    // attn_out projection, 128^2 tiles, split-K=2 -> two bf16 partial buffers
    gemm_bf2<<<512, 256, 0, stream>>>(ctx_b, wattn_b, f1a, f1b, D, D);

    lnmean_kernel<<<dim3(B, 8), 256, 0, stream>>>(f1a, f1b, attn_out_b, ln_g, ln_b, counts, msum);

    tproj_kernel<<<256, 256, 0, stream>>>(msum, proj_w, proj_b, out);
}